// Round 1
// baseline (191.281 us; speedup 1.0000x reference)
//
#include <hip/hip_runtime.h>
#include <math.h>

// Problem constants (from reference): b=1, c=64, h=48, w=84, cq=32, nref=3
constexpr int H  = 48;
constexpr int W  = 84;
constexpr int HW = H * W;      // 4032
constexpr int C  = 64;
constexpr int CQ = 32;
constexpr int QH = 192;
constexpr int QW = 336;
constexpr int NREF = 3;

#define DEV __device__ __forceinline__

DEV float dot64(const float* __restrict__ a, const float* __restrict__ b) {
  float s = 0.f;
#pragma unroll
  for (int c = 0; c < 64; c += 4) {
    float4 av = *reinterpret_cast<const float4*>(a + c);
    float4 bv = *reinterpret_cast<const float4*>(b + c);
    s = fmaf(av.x, bv.x, s);
    s = fmaf(av.y, bv.y, s);
    s = fmaf(av.z, bv.z, s);
    s = fmaf(av.w, bv.w, s);
  }
  return s;
}

// 256-thread (4-wave) block reductions. Leading barrier protects scratch reuse.
DEV float block_sum(float v, float* red) {
  __syncthreads();
#pragma unroll
  for (int o = 32; o > 0; o >>= 1) v += __shfl_down(v, o, 64);
  if ((threadIdx.x & 63) == 0) red[threadIdx.x >> 6] = v;
  __syncthreads();
  return red[0] + red[1] + red[2] + red[3];
}

DEV float block_max(float v, float* red) {
  __syncthreads();
#pragma unroll
  for (int o = 32; o > 0; o >>= 1) v = fmaxf(v, __shfl_down(v, o, 64));
  if ((threadIdx.x & 63) == 0) red[threadIdx.x >> 6] = v;
  __syncthreads();
  return fmaxf(fmaxf(red[0], red[1]), fmaxf(red[2], red[3]));
}

// Transpose feats_r (3 refs) and feats_t (blockIdx.y==3) from [c][pix] to [pix][c].
__global__ __launch_bounds__(256) void k_transpose(const float* __restrict__ fr,
                                                   const float* __restrict__ ft,
                                                   float* __restrict__ frT,
                                                   float* __restrict__ ftT) {
  __shared__ float lds[64][65];
  const int r = blockIdx.y;
  const float* src = (r < NREF) ? (fr + (size_t)r * C * HW) : ft;
  float* dst       = (r < NREF) ? (frT + (size_t)r * HW * C) : ftT;
  const int pb = blockIdx.x * 64;                 // HW = 63*64
  const int a = threadIdx.x & 63, b = threadIdx.x >> 6;
#pragma unroll
  for (int i = 0; i < 16; i++) {
    int c = i * 4 + b;
    lds[c][a] = src[c * HW + pb + a];             // coalesced read
  }
  __syncthreads();
#pragma unroll
  for (int i = 0; i < 16; i++) {
    int p = i * 4 + b;
    dst[(pb + p) * C + a] = lds[a][p];            // coalesced write, conflict-free LDS
  }
}

// Gather quantized_r[:, :, ::4, ::4] into dense channel-last [k][y][x][c].
__global__ __launch_bounds__(256) void k_qr(const float* __restrict__ q,
                                            float* __restrict__ qrdT) {
  const int yq = blockIdx.x, k = blockIdx.y;
  const int c = threadIdx.x & 31;
  for (int x = threadIdx.x >> 5; x < W; x += 8) {
    qrdT[(size_t)((k * H + yq) * W + x) * CQ + c] =
        q[(size_t)((k * CQ + c) * QH + yq * 4) * QW + x * 4];
  }
}

// Per-pixel 25x25 dilated correlation -> softmax -> expected offsets.
__global__ __launch_bounds__(256) void k_offsets(const float* __restrict__ frT,
                                                 const float* __restrict__ ftT,
                                                 const int* __restrict__ ridx,
                                                 const int* __restrict__ curp,
                                                 float* __restrict__ offs) {
  const int si = blockIdx.y;
  const int gap = curp[0] - ridx[si];
  if (gap <= 15) return;                      // not a "search" ref
  int d = gap / 15 + 1;
  if (d > 4) d = 4;

  const int pix = blockIdx.x;
  const int y = pix / W, x = pix - y * W;
  const int tid = threadIdx.x;

  __shared__ __align__(16) float tl[64];
  __shared__ float red[4];

  if (tid < 64) tl[tid] = ftT[pix * C + tid];
  __syncthreads();

  const float* rb = frT + (size_t)si * HW * C;

  float lv[3];
#pragma unroll
  for (int j = 0; j < 3; j++) {
    const int idx = tid + j * 256;
    float s = 0.f;
    if (idx < 625) {
      const int p = idx / 25, qq = idx - p * 25;
      const int y2 = y + d * (p - 12), x2 = x + d * (qq - 12);
      if ((unsigned)y2 < (unsigned)H && (unsigned)x2 < (unsigned)W)
        s = dot64(tl, rb + (y2 * W + x2) * C);
    }
    lv[j] = s;                                 // OOB -> logit 0 (zero padding)
  }

  float m = -1e30f;
#pragma unroll
  for (int j = 0; j < 3; j++)
    if (tid + j * 256 < 625) m = fmaxf(m, lv[j]);
  m = block_max(m, red);

  float se = 0.f, sy = 0.f, sx = 0.f;
#pragma unroll
  for (int j = 0; j < 3; j++) {
    const int idx = tid + j * 256;
    if (idx < 625) {
      const int p = idx / 25, qq = idx - p * 25;
      const float e = expf(lv[j] - m);
      se += e;
      sy += e * (float)(p - 12);
      sx += e * (float)(qq - 12);
    }
  }
  se = block_sum(se, red);
  sy = block_sum(sy, red);
  sx = block_sum(sx, red);
  if (tid == 0) {
    const float inv = 1.f / se;
    offs[(si * HW + pix) * 2 + 0] = (float)d * sy * inv;   // off_y
    offs[(si * HW + pix) * 2 + 1] = (float)d * sx * inv;   // off_x
  }
}

// Per-pixel: 507 logits -> joint softmax -> fused output gather (32 channels).
__global__ __launch_bounds__(256) void k_main(const float* __restrict__ frT,
                                              const float* __restrict__ ftT,
                                              const float* __restrict__ qrdT,
                                              const int* __restrict__ ridx,
                                              const int* __restrict__ curp,
                                              const float* __restrict__ offs,
                                              float* __restrict__ out) {
  const int pix = blockIdx.x;
  const int y = pix / W, x = pix - y * W;
  const int tid = threadIdx.x;

  __shared__ __align__(16) float tl[64];
  __shared__ float lg[507];     // logits, then unnormalized softmax weights
  __shared__ float C14[196];    // 14x14 integer correlation field (search refs)
  __shared__ float Wb[196];     // bilinearly blurred weights (search refs)
  __shared__ float red[4];
  __shared__ float part[256];

  const int cur = curp[0];
  bool srch[NREF];
  int ls = -1;                  // last search ref (reference reuses ITS py/px for output)
#pragma unroll
  for (int k = 0; k < NREF; k++) {
    const int g = cur - ridx[k];
    srch[k] = (g > 15);
    if (srch[k]) ls = k;
  }

  if (tid < 64) tl[tid] = ftT[pix * C + tid];
  __syncthreads();

  // ---- logits ----
  for (int k = 0; k < NREF; k++) {
    const float* rb = frT + (size_t)k * HW * C;
    if (srch[k]) {
      const float oy = offs[(k * HW + pix) * 2 + 0];
      const float ox = offs[(k * HW + pix) * 2 + 1];
      const float fy = (float)y + oy, fx = (float)x + ox;
      const float Y0 = floorf(fy), X0 = floorf(fx);
      const float wy = fy - Y0, wx = fx - X0;
      const int iY = (int)Y0, iX = (int)X0;
      for (int idx = tid; idx < 196; idx += 256) {
        const int i = idx / 14, j = idx - i * 14;
        const int row = iY + i - 6, col = iX + j - 6;
        float s = 0.f;
        if ((unsigned)row < (unsigned)H && (unsigned)col < (unsigned)W)
          s = dot64(tl, rb + (row * W + col) * C);
        C14[idx] = s;
      }
      __syncthreads();
      for (int idx = tid; idx < 169; idx += 256) {
        const int p = idx / 13, q = idx - p * 13;
        const float* cp = C14 + p * 14 + q;
        lg[k * 169 + idx] = (1.f - wy) * ((1.f - wx) * cp[0] + wx * cp[1]) +
                            wy * ((1.f - wx) * cp[14] + wx * cp[15]);
      }
      __syncthreads();   // C14 may be reused by another search ref
    } else {
      for (int idx = tid; idx < 169; idx += 256) {
        const int p = idx / 13, q = idx - p * 13;
        const int row = y + p - 6, col = x + q - 6;
        float s = 0.f;
        if ((unsigned)row < (unsigned)H && (unsigned)col < (unsigned)W)
          s = dot64(tl, rb + (row * W + col) * C);
        lg[k * 169 + idx] = s;
      }
    }
  }
  __syncthreads();

  // ---- softmax over 507 (keep unnormalized e's, scale output by 1/sum) ----
  float m = -1e30f;
  for (int i = tid; i < 507; i += 256) m = fmaxf(m, lg[i]);
  m = block_max(m, red);
  float se = 0.f;
  for (int i = tid; i < 507; i += 256) {
    const float e = expf(lg[i] - m);
    lg[i] = e;
    se += e;
  }
  se = block_sum(se, red);
  const float inv = 1.f / se;

  // ---- fused output gather: thread = (group g, channel c0) ----
  const int c0 = tid & 31, g = tid >> 5;
  float acc = 0.f;
  float lwy = 0.f, lwx = 0.f;
  int lY = 0, lX = 0;
  if (ls >= 0) {
    const float oy = offs[(ls * HW + pix) * 2 + 0];
    const float ox = offs[(ls * HW + pix) * 2 + 1];
    const float fy = (float)y + oy, fx = (float)x + ox;
    const float Y0 = floorf(fy), X0 = floorf(fx);
    lwy = fy - Y0; lwx = fx - X0; lY = (int)Y0; lX = (int)X0;
  }

  for (int k = 0; k < NREF; k++) {
    const float* qb = qrdT + (size_t)k * HW * CQ;
    if (srch[k]) {
      __syncthreads();     // protect Wb reuse
      const float* wk = lg + k * 169;
      for (int idx = tid; idx < 196; idx += 256) {
        const int i = idx / 14, j = idx - i * 14;
        const float a00 = (i < 13 && j < 13) ? wk[i * 13 + j] : 0.f;
        const float a01 = (i < 13 && j >= 1) ? wk[i * 13 + j - 1] : 0.f;
        const float a10 = (i >= 1 && j < 13) ? wk[(i - 1) * 13 + j] : 0.f;
        const float a11 = (i >= 1 && j >= 1) ? wk[(i - 1) * 13 + j - 1] : 0.f;
        Wb[idx] = (1.f - lwy) * ((1.f - lwx) * a00 + lwx * a01) +
                  lwy * ((1.f - lwx) * a10 + lwx * a11);
      }
      __syncthreads();
      for (int idx = g; idx < 196; idx += 8) {
        const int i = idx / 14, j = idx - i * 14;
        const int row = lY + i - 6, col = lX + j - 6;
        if ((unsigned)row < (unsigned)H && (unsigned)col < (unsigned)W)
          acc += Wb[idx] * qb[(size_t)(row * W + col) * CQ + c0];
      }
    } else {
      const float* wk = lg + k * 169;
      for (int idx = g; idx < 169; idx += 8) {
        const int p = idx / 13, q = idx - p * 13;
        const int row = y + p - 6, col = x + q - 6;
        if ((unsigned)row < (unsigned)H && (unsigned)col < (unsigned)W)
          acc += wk[idx] * qb[(size_t)(row * W + col) * CQ + c0];
      }
    }
  }

  part[tid] = acc * inv;
  __syncthreads();
  if (tid < 32) {
    float s = 0.f;
#pragma unroll
    for (int gg = 0; gg < 8; gg++) s += part[gg * 32 + tid];
    out[tid * HW + pix] = s;   // out[c][y][x]
  }
}

extern "C" void kernel_launch(void* const* d_in, const int* in_sizes, int n_in,
                              void* d_out, int out_size, void* d_ws, size_t ws_size,
                              hipStream_t stream) {
  (void)in_sizes; (void)n_in; (void)out_size; (void)ws_size;
  const float* fr = (const float*)d_in[0];   // feats_r      (3,1,64,48,84)
  const float* ft = (const float*)d_in[1];   // feats_t      (1,64,48,84)
  const float* q  = (const float*)d_in[2];   // quantized_r  (3,1,32,192,336)
  const int* ridx = (const int*)d_in[3];     // ref_index    (3,)
  const int* cur  = (const int*)d_in[4];     // current_ind  (1,)
  float* out = (float*)d_out;
  float* ws  = (float*)d_ws;

  float* frT  = ws;                          // 3*4032*64 = 774144 floats
  float* ftT  = frT + (size_t)NREF * HW * C; // 258048 floats
  float* qrdT = ftT + (size_t)HW * C;        // 3*4032*32 = 387072 floats
  float* offs = qrdT + (size_t)NREF * HW * CQ; // 3*4032*2 floats

  k_transpose<<<dim3(HW / 64, NREF + 1), dim3(256), 0, stream>>>(fr, ft, frT, ftT);
  k_qr<<<dim3(H, NREF), dim3(256), 0, stream>>>(q, qrdT);
  k_offsets<<<dim3(HW, NREF), dim3(256), 0, stream>>>(frT, ftT, ridx, cur, offs);
  k_main<<<dim3(HW), dim3(256), 0, stream>>>(frT, ftT, qrdT, ridx, cur, offs, out);
}